// Round 1
// baseline (598.070 us; speedup 1.0000x reference)
//
#include <hip/hip_runtime.h>
#include <hip/hip_bf16.h>

#define G_N 96
#define N_N 250
#define N_P 256
#define E_N 64
#define OUT_GSTRIDE (250 * 750)          // per-graph slab inside one output tensor (floats)
#define OUT_STRIDE  (96 * 250 * 750)     // 18,000,000 floats per output tensor

typedef __attribute__((ext_vector_type(4))) float floatx4;
typedef __attribute__((ext_vector_type(8))) short shortx8;
typedef __attribute__((ext_vector_type(4))) short shortx4;

__device__ __forceinline__ float bf2f(unsigned short u) {
    union { unsigned int i; float f; } v; v.i = ((unsigned int)u) << 16; return v.f;
}
__device__ __forceinline__ unsigned short f2bf(float f) {
    union { float f; unsigned int i; } v; v.f = f;
    unsigned int x = v.i;
    return (unsigned short)((x + 0x7fffu + ((x >> 16) & 1u)) >> 16);  // RNE
}

// ---------------------------------------------------------------------------
// K1: nodevec = tanh(concat(hist,prior,obs) @ W + b)  -> bf16 [96][256][64]
// fp32 vector GEMM, 64x64 tile per block, 4x4 register blocking.
// Padded rows (n>=250) are written as zero so all downstream padding is zero.
// ---------------------------------------------------------------------------
__global__ __launch_bounds__(256) void k_embed(
    const float* __restrict__ hist, const float* __restrict__ prior,
    const float* __restrict__ obs, const float* __restrict__ Wemb,
    const float* __restrict__ bemb, unsigned short* __restrict__ nvb)
{
    __shared__ __attribute__((aligned(16))) float Xt[32][68];  // [k][n], pad 68
    __shared__ __attribute__((aligned(16))) float Wl[32][64];  // [k][e]
    const int t  = threadIdx.x;
    const int tx = t & 15, ty = t >> 4;
    const int rr0 = blockIdx.x * 64;   // padded row base; 64 | 256 so g uniform
    const int g   = rr0 >> 8;
    const int n0  = rr0 & 255;

    float acc[4][4] = {};

    for (int c = 0; c < 7; ++c) {      // 7 K-chunks of 32; source boundaries align
        const float* src; int rowlen, off;
        if (c < 4)      { src = hist;  rowlen = 128; off = c << 5; }
        else if (c < 6) { src = prior; rowlen = 64;  off = (c - 4) << 5; }
        else            { src = obs;   rowlen = 32;  off = 0; }
        __syncthreads();
        {   // stage X chunk transposed: 64 rows x 32 d
            const int d  = t & 31;
            const int nb = t >> 5;
            #pragma unroll
            for (int p = 0; p < 8; ++p) {
                const int nl = nb + p * 8;
                const int n  = n0 + nl;
                float v = 0.0f;
                if (n < N_N) v = src[(size_t)(g * N_N + n) * rowlen + off + d];
                Xt[d][nl] = v;
            }
        }
        {   // stage W chunk: 32 d x 64 e
            const int e  = t & 63;
            const int db = t >> 6;
            #pragma unroll
            for (int p = 0; p < 8; ++p) {
                const int dl = db + p * 4;
                Wl[dl][e] = Wemb[(c * 32 + dl) * 64 + e];
            }
        }
        __syncthreads();
        #pragma unroll
        for (int k = 0; k < 32; ++k) {
            const float4 av = *(const float4*)&Xt[k][4 * ty];
            const float4 bv = *(const float4*)&Wl[k][4 * tx];
            const float a[4] = {av.x, av.y, av.z, av.w};
            const float b[4] = {bv.x, bv.y, bv.z, bv.w};
            #pragma unroll
            for (int r = 0; r < 4; ++r)
                #pragma unroll
                for (int cc = 0; cc < 4; ++cc)
                    acc[r][cc] = fmaf(a[r], b[cc], acc[r][cc]);
        }
    }
    #pragma unroll
    for (int r = 0; r < 4; ++r) {
        const int nl = 4 * ty + r;
        const int n  = n0 + nl;
        unsigned short* d2 = nvb + ((size_t)g * N_P + (n0 + nl)) * E_N + 4 * tx;
        #pragma unroll
        for (int cc = 0; cc < 4; ++cc) {
            float v = 0.0f;
            if (n < N_N) v = tanhf(acc[r][cc] + bemb[4 * tx + cc]);
            d2[cc] = f2bf(v);
        }
    }
}

// ---------------------------------------------------------------------------
// K2a: S = relu(nv @ nv^T) per graph (bf16 MFMA 16x16x32, K=64) + fp32
// rowsums. Block owns 16 full rows (256 cols) -> rowsum needs no atomics.
// ---------------------------------------------------------------------------
__global__ __launch_bounds__(256) void k_sim(
    const unsigned short* __restrict__ nvb, unsigned short* __restrict__ Sb,
    float* __restrict__ rowsum)
{
    const int blk = blockIdx.x;          // 96*16
    const int g   = blk >> 4;
    const int i0  = (blk & 15) << 4;
    const int t    = threadIdx.x;
    const int w    = t >> 6;
    const int lane = t & 63;
    const int m = lane & 15, kg = lane >> 4;

    const shortx8* nvg = (const shortx8*)(nvb + (size_t)g * N_P * E_N);
    const shortx8 a0 = nvg[(i0 + m) * 8 + kg];       // k in [8kg, 8kg+8)
    const shortx8 a1 = nvg[(i0 + m) * 8 + 4 + kg];   // k in [32+8kg, ...)

    floatx4 acc[4];
    const floatx4 zero = {0.f, 0.f, 0.f, 0.f};
    #pragma unroll
    for (int tt = 0; tt < 4; ++tt) {
        const int j = (w << 6) + (tt << 4) + m;      // B-frag: n=lane&15, row-major nv
        const shortx8 b0 = nvg[j * 8 + kg];
        const shortx8 b1 = nvg[j * 8 + 4 + kg];
        floatx4 c = zero;
        c = __builtin_amdgcn_mfma_f32_16x16x32_bf16(a0, b0, c, 0, 0, 0);
        c = __builtin_amdgcn_mfma_f32_16x16x32_bf16(a1, b1, c, 0, 0, 0);
        acc[tt] = c;
    }

    float v[4] = {0.f, 0.f, 0.f, 0.f};
    unsigned short* Sg = Sb + (size_t)g * N_P * N_P;
    #pragma unroll
    for (int tt = 0; tt < 4; ++tt) {
        #pragma unroll
        for (int r = 0; r < 4; ++r) {
            float s = acc[tt][r];
            s = s > 0.f ? s : 0.f;                   // relu
            const int il = (kg << 2) + r;            // C/D: row=(lane>>4)*4+reg
            const int j  = (w << 6) + (tt << 4) + m; // col=lane&15
            Sg[(size_t)(i0 + il) * N_P + j] = f2bf(s);
            v[r] += s;
        }
    }
    #pragma unroll
    for (int r = 0; r < 4; ++r) {                    // reduce over m (16 lanes)
        v[r] += __shfl_xor(v[r], 1);
        v[r] += __shfl_xor(v[r], 2);
        v[r] += __shfl_xor(v[r], 4);
        v[r] += __shfl_xor(v[r], 8);
    }
    __shared__ float rs[4][16];
    if (m == 0) {
        #pragma unroll
        for (int r = 0; r < 4; ++r) rs[w][(kg << 2) + r] = v[r];
    }
    __syncthreads();
    if (t < 16) rowsum[g * N_P + i0 + t] = rs[0][t] + rs[1][t] + rs[2][t] + rs[3][t];
}

// ---------------------------------------------------------------------------
// K2b: t_i = sum_j S_ij d_j ; r=1/(d_i t_i+1e-9); c=r*d; w=c*d
// Wave-per-row: lane covers 4 cols (8B coalesced loads), full-wave shfl
// reduce. 96*64 blocks (was 96 -> latency/occupancy-bound).
// ---------------------------------------------------------------------------
__global__ __launch_bounds__(256) void k_trans(
    const unsigned short* __restrict__ Sb, const float* __restrict__ rowsum,
    float* __restrict__ cArr, float* __restrict__ wArr)
{
    const int blk = (blockIdx.x & 7) * 768 + (blockIdx.x >> 3);  // XCD swizzle, 6144 blocks
    const int g  = blk >> 6;
    const int r0 = (blk & 63) << 2;      // 4 rows per block, one per wave
    const int t = threadIdx.x;
    const int w = t >> 6, lane = t & 63;
    __shared__ __attribute__((aligned(16))) float dL[N_P];
    dL[t] = rsqrtf(rowsum[g * N_P + t] + 1e-9f);
    __syncthreads();
    const int row = r0 + w;
    const shortx4 sv = *(const shortx4*)(Sb + (size_t)g * N_P * N_P
                                         + (size_t)row * N_P + lane * 4);
    const float4 dv = *(const float4*)&dL[lane * 4];
    float a = bf2f((unsigned short)sv[0]) * dv.x
            + bf2f((unsigned short)sv[1]) * dv.y
            + bf2f((unsigned short)sv[2]) * dv.z
            + bf2f((unsigned short)sv[3]) * dv.w;
    #pragma unroll
    for (int s = 32; s; s >>= 1) a += __shfl_xor(a, s);
    if (lane == 0) {
        const float d = dL[row];
        const float r = 1.0f / (d * a + 1e-9f);
        const float c = r * d;
        cArr[g * N_P + row] = c;
        wArr[g * N_P + row] = c * d;
    }
}

// ---------------------------------------------------------------------------
// K3 (fused): M = (S*diag(w)) @ S^T per graph (w folded into A-frag).
// Q = Dd M Dc -> out1/out3; P = Dd S Dc -> out0/out2 (S re-read, L2-hot).
// Writes ALL 288 MB of output from one BW-saturating kernel; nontemporal
// stores keep the write stream out of L2 (S + nv stay resident).
// XCD swizzle: 16 blocks/graph land on one XCD -> 1.5 MB S footprint / L2.
// ---------------------------------------------------------------------------
__global__ __launch_bounds__(256) void k_pp(
    const unsigned short* __restrict__ Sb, const float* __restrict__ rowsum,
    const float* __restrict__ cArr, const float* __restrict__ wArr,
    float* __restrict__ out)
{
    const int blk = (blockIdx.x & 7) * 192 + (blockIdx.x >> 3);  // XCD swizzle, 1536 blocks
    const int g   = blk >> 4;
    const int i0  = ((blk >> 2) & 3) << 6;
    const int j0  = (blk & 3) << 6;
    const int t    = threadIdx.x;
    const int w    = t >> 6;
    const int lane = t & 63;
    const int m = lane & 15, kg = lane >> 4;

    __shared__ __attribute__((aligned(16))) unsigned short As[64][40]; // 80B stride
    __shared__ __attribute__((aligned(16))) unsigned short Bs[64][40];
    __shared__ float dRow[64], cCol[64];
    __shared__ __attribute__((aligned(16))) float wL[N_P];

    if (t < 64) dRow[t] = rsqrtf(rowsum[g * N_P + i0 + t] + 1e-9f);
    else if (t < 128) cCol[t - 64] = cArr[g * N_P + j0 + (t - 64)];
    wL[t] = wArr[g * N_P + t];

    const unsigned short* Sg = Sb + (size_t)g * N_P * N_P;

    floatx4 acc[4];
    const floatx4 zero = {0.f, 0.f, 0.f, 0.f};
    #pragma unroll
    for (int tt = 0; tt < 4; ++tt) acc[tt] = zero;

    const int sr = t >> 2, sc = t & 3;   // staging: 16B per thread per matrix
    for (int kb = 0; kb < 8; ++kb) {
        __syncthreads();
        *(uint4*)&As[sr][sc * 8] = *(const uint4*)(Sg + (size_t)(i0 + sr) * N_P + kb * 32 + sc * 8);
        *(uint4*)&Bs[sr][sc * 8] = *(const uint4*)(Sg + (size_t)(j0 + sr) * N_P + kb * 32 + sc * 8);
        __syncthreads();
        const shortx8 a = *(const shortx8*)&As[(w << 4) + m][kg << 3];
        const float4 w0 = *(const float4*)&wL[kb * 32 + (kg << 3)];
        const float4 w1 = *(const float4*)&wL[kb * 32 + (kg << 3) + 4];
        const float wv[8] = {w0.x, w0.y, w0.z, w0.w, w1.x, w1.y, w1.z, w1.w};
        shortx8 aw;
        #pragma unroll
        for (int u = 0; u < 8; ++u)
            aw[u] = (short)f2bf(bf2f((unsigned short)a[u]) * wv[u]);
        #pragma unroll
        for (int tt = 0; tt < 4; ++tt) {
            const shortx8 b = *(const shortx8*)&Bs[(tt << 4) + m][kg << 3];
            acc[tt] = __builtin_amdgcn_mfma_f32_16x16x32_bf16(aw, b, acc[tt], 0, 0, 0);
        }
    }

    // ---- epilogue: hoist S tile reads (L2 hits), then stream all 4 outputs
    float sv[4][4];
    float dR[4], cC[4];
    #pragma unroll
    for (int r = 0; r < 4; ++r) dR[r] = dRow[(w << 4) + (kg << 2) + r];
    #pragma unroll
    for (int tt = 0; tt < 4; ++tt) cC[tt] = cCol[(tt << 4) + m];
    #pragma unroll
    for (int tt = 0; tt < 4; ++tt) {
        #pragma unroll
        for (int r = 0; r < 4; ++r) {
            const int I = i0 + (w << 4) + (kg << 2) + r;
            const int J = j0 + (tt << 4) + m;
            sv[tt][r] = (I < N_N && J < N_N) ? bf2f(Sg[(size_t)I * N_P + J]) : 0.f;
        }
    }

    float* o0 = out + (size_t)g * OUT_GSTRIDE;
    float* o1 = o0 + (size_t)OUT_STRIDE;
    float* o2 = o0 + 2 * (size_t)OUT_STRIDE;
    float* o3 = o0 + 3 * (size_t)OUT_STRIDE;
    #pragma unroll
    for (int tt = 0; tt < 4; ++tt) {
        #pragma unroll
        for (int r = 0; r < 4; ++r) {
            const int iL = (w << 4) + (kg << 2) + r;
            const int jL = (tt << 4) + m;
            const int I = i0 + iL, J = j0 + jL;
            if (I < N_N && J < N_N) {
                const float dc = dR[r] * cC[tt];
                const float p = (I == J) ? 0.f : sv[tt][r] * dc;
                const float q = (I == J) ? 0.f : acc[tt][r] * dc;
                const size_t base = (size_t)I * 750 + J;
                __builtin_nontemporal_store(p, o0 + base);
                __builtin_nontemporal_store(p, o0 + base + 250);
                __builtin_nontemporal_store(p, o0 + base + 500);
                __builtin_nontemporal_store(q, o1 + base);
                __builtin_nontemporal_store(q, o1 + base + 250);
                __builtin_nontemporal_store(q, o1 + base + 500);
                __builtin_nontemporal_store(p, o2 + base);
                __builtin_nontemporal_store(p, o2 + base + 250);
                __builtin_nontemporal_store(p, o2 + base + 500);
                __builtin_nontemporal_store(q, o3 + base);
                __builtin_nontemporal_store(q, o3 + base + 250);
                __builtin_nontemporal_store(q, o3 + base + 500);
            }
        }
    }
}

extern "C" void kernel_launch(void* const* d_in, const int* in_sizes, int n_in,
                              void* d_out, int out_size, void* d_ws, size_t ws_size,
                              hipStream_t stream) {
    const float* hist  = (const float*)d_in[0];
    const float* prior = (const float*)d_in[1];
    const float* obs   = (const float*)d_in[2];
    const float* Wemb  = (const float*)d_in[3];
    const float* bemb  = (const float*)d_in[4];
    float* out = (float*)d_out;

    char* p = (char*)d_ws;
    unsigned short* nvb = (unsigned short*)p; p += (size_t)G_N * N_P * E_N * 2;   // 3.1 MB
    unsigned short* Sb  = (unsigned short*)p; p += (size_t)G_N * N_P * N_P * 2;   // 12.6 MB
    float* rowsum = (float*)p; p += (size_t)G_N * N_P * 4;
    float* cArr   = (float*)p; p += (size_t)G_N * N_P * 4;
    float* wArr   = (float*)p; p += (size_t)G_N * N_P * 4;
    // total ~16 MB of ws

    k_embed<<<dim3(G_N * N_P / 64), dim3(256), 0, stream>>>(hist, prior, obs, Wemb, bemb, nvb);
    k_sim  <<<dim3(G_N * 16),       dim3(256), 0, stream>>>(nvb, Sb, rowsum);
    k_trans<<<dim3(G_N * 64),       dim3(256), 0, stream>>>(Sb, rowsum, cArr, wArr);
    k_pp   <<<dim3(G_N * 16),       dim3(256), 0, stream>>>(Sb, rowsum, cArr, wArr, out);
}

// Round 2
// 435.265 us; speedup vs baseline: 1.3740x; 1.3740x over previous
//
#include <hip/hip_runtime.h>
#include <hip/hip_bf16.h>

#define G_N 96
#define N_N 250
#define N_P 256
#define E_N 64
#define OUT_GSTRIDE (250 * 750)          // per-graph slab inside one output tensor (floats)
#define OUT_STRIDE  (96 * 250 * 750)     // 18,000,000 floats per output tensor

typedef __attribute__((ext_vector_type(4))) float floatx4;
typedef __attribute__((ext_vector_type(8))) short shortx8;
typedef __attribute__((ext_vector_type(4))) short shortx4;

__device__ __forceinline__ float bf2f(unsigned short u) {
    union { unsigned int i; float f; } v; v.i = ((unsigned int)u) << 16; return v.f;
}
__device__ __forceinline__ unsigned short f2bf(float f) {
    union { float f; unsigned int i; } v; v.f = f;
    unsigned int x = v.i;
    return (unsigned short)((x + 0x7fffu + ((x >> 16) & 1u)) >> 16);  // RNE
}

// ---------------------------------------------------------------------------
// K1: nodevec = tanh(concat(hist,prior,obs) @ W + b)  -> bf16 [96][256][64]
// fp32 vector GEMM, 64x64 tile per block, 4x4 register blocking.
// Padded rows (n>=250) are written as zero so all downstream padding is zero.
// ---------------------------------------------------------------------------
__global__ __launch_bounds__(256) void k_embed(
    const float* __restrict__ hist, const float* __restrict__ prior,
    const float* __restrict__ obs, const float* __restrict__ Wemb,
    const float* __restrict__ bemb, unsigned short* __restrict__ nvb)
{
    __shared__ __attribute__((aligned(16))) float Xt[32][68];  // [k][n], pad 68
    __shared__ __attribute__((aligned(16))) float Wl[32][64];  // [k][e]
    const int t  = threadIdx.x;
    const int tx = t & 15, ty = t >> 4;
    const int rr0 = blockIdx.x * 64;   // padded row base; 64 | 256 so g uniform
    const int g   = rr0 >> 8;
    const int n0  = rr0 & 255;

    float acc[4][4] = {};

    for (int c = 0; c < 7; ++c) {      // 7 K-chunks of 32; source boundaries align
        const float* src; int rowlen, off;
        if (c < 4)      { src = hist;  rowlen = 128; off = c << 5; }
        else if (c < 6) { src = prior; rowlen = 64;  off = (c - 4) << 5; }
        else            { src = obs;   rowlen = 32;  off = 0; }
        __syncthreads();
        {   // stage X chunk transposed: 64 rows x 32 d
            const int d  = t & 31;
            const int nb = t >> 5;
            #pragma unroll
            for (int p = 0; p < 8; ++p) {
                const int nl = nb + p * 8;
                const int n  = n0 + nl;
                float v = 0.0f;
                if (n < N_N) v = src[(size_t)(g * N_N + n) * rowlen + off + d];
                Xt[d][nl] = v;
            }
        }
        {   // stage W chunk: 32 d x 64 e
            const int e  = t & 63;
            const int db = t >> 6;
            #pragma unroll
            for (int p = 0; p < 8; ++p) {
                const int dl = db + p * 4;
                Wl[dl][e] = Wemb[(c * 32 + dl) * 64 + e];
            }
        }
        __syncthreads();
        #pragma unroll
        for (int k = 0; k < 32; ++k) {
            const float4 av = *(const float4*)&Xt[k][4 * ty];
            const float4 bv = *(const float4*)&Wl[k][4 * tx];
            const float a[4] = {av.x, av.y, av.z, av.w};
            const float b[4] = {bv.x, bv.y, bv.z, bv.w};
            #pragma unroll
            for (int r = 0; r < 4; ++r)
                #pragma unroll
                for (int cc = 0; cc < 4; ++cc)
                    acc[r][cc] = fmaf(a[r], b[cc], acc[r][cc]);
        }
    }
    #pragma unroll
    for (int r = 0; r < 4; ++r) {
        const int nl = 4 * ty + r;
        const int n  = n0 + nl;
        unsigned short* d2 = nvb + ((size_t)g * N_P + (n0 + nl)) * E_N + 4 * tx;
        #pragma unroll
        for (int cc = 0; cc < 4; ++cc) {
            float v = 0.0f;
            if (n < N_N) v = tanhf(acc[r][cc] + bemb[4 * tx + cc]);
            d2[cc] = f2bf(v);
        }
    }
}

// ---------------------------------------------------------------------------
// K2a: S = relu(nv @ nv^T) per graph (bf16 MFMA 16x16x32, K=64) + fp32
// rowsums. Block owns 16 full rows (256 cols) -> rowsum needs no atomics.
// ---------------------------------------------------------------------------
__global__ __launch_bounds__(256) void k_sim(
    const unsigned short* __restrict__ nvb, unsigned short* __restrict__ Sb,
    float* __restrict__ rowsum)
{
    const int blk = blockIdx.x;          // 96*16
    const int g   = blk >> 4;
    const int i0  = (blk & 15) << 4;
    const int t    = threadIdx.x;
    const int w    = t >> 6;
    const int lane = t & 63;
    const int m = lane & 15, kg = lane >> 4;

    const shortx8* nvg = (const shortx8*)(nvb + (size_t)g * N_P * E_N);
    const shortx8 a0 = nvg[(i0 + m) * 8 + kg];       // k in [8kg, 8kg+8)
    const shortx8 a1 = nvg[(i0 + m) * 8 + 4 + kg];   // k in [32+8kg, ...)

    floatx4 acc[4];
    const floatx4 zero = {0.f, 0.f, 0.f, 0.f};
    #pragma unroll
    for (int tt = 0; tt < 4; ++tt) {
        const int j = (w << 6) + (tt << 4) + m;      // B-frag: n=lane&15, row-major nv
        const shortx8 b0 = nvg[j * 8 + kg];
        const shortx8 b1 = nvg[j * 8 + 4 + kg];
        floatx4 c = zero;
        c = __builtin_amdgcn_mfma_f32_16x16x32_bf16(a0, b0, c, 0, 0, 0);
        c = __builtin_amdgcn_mfma_f32_16x16x32_bf16(a1, b1, c, 0, 0, 0);
        acc[tt] = c;
    }

    float v[4] = {0.f, 0.f, 0.f, 0.f};
    unsigned short* Sg = Sb + (size_t)g * N_P * N_P;
    #pragma unroll
    for (int tt = 0; tt < 4; ++tt) {
        #pragma unroll
        for (int r = 0; r < 4; ++r) {
            float s = acc[tt][r];
            s = s > 0.f ? s : 0.f;                   // relu
            const int il = (kg << 2) + r;            // C/D: row=(lane>>4)*4+reg
            const int j  = (w << 6) + (tt << 4) + m; // col=lane&15
            Sg[(size_t)(i0 + il) * N_P + j] = f2bf(s);
            v[r] += s;
        }
    }
    #pragma unroll
    for (int r = 0; r < 4; ++r) {                    // reduce over m (16 lanes)
        v[r] += __shfl_xor(v[r], 1);
        v[r] += __shfl_xor(v[r], 2);
        v[r] += __shfl_xor(v[r], 4);
        v[r] += __shfl_xor(v[r], 8);
    }
    __shared__ float rs[4][16];
    if (m == 0) {
        #pragma unroll
        for (int r = 0; r < 4; ++r) rs[w][(kg << 2) + r] = v[r];
    }
    __syncthreads();
    if (t < 16) rowsum[g * N_P + i0 + t] = rs[0][t] + rs[1][t] + rs[2][t] + rs[3][t];
}

// ---------------------------------------------------------------------------
// K2b: t_i = sum_j S_ij d_j ; r=1/(d_i t_i+1e-9); c=r*d; w=c*d
// Wave-per-row: lane covers 4 cols (8B coalesced loads), full-wave shfl
// reduce. 96*64 blocks.
// ---------------------------------------------------------------------------
__global__ __launch_bounds__(256) void k_trans(
    const unsigned short* __restrict__ Sb, const float* __restrict__ rowsum,
    float* __restrict__ cArr, float* __restrict__ wArr)
{
    const int blk = (blockIdx.x & 7) * 768 + (blockIdx.x >> 3);  // XCD swizzle, 6144 blocks
    const int g  = blk >> 6;
    const int r0 = (blk & 63) << 2;      // 4 rows per block, one per wave
    const int t = threadIdx.x;
    const int w = t >> 6, lane = t & 63;
    __shared__ __attribute__((aligned(16))) float dL[N_P];
    dL[t] = rsqrtf(rowsum[g * N_P + t] + 1e-9f);
    __syncthreads();
    const int row = r0 + w;
    const shortx4 sv = *(const shortx4*)(Sb + (size_t)g * N_P * N_P
                                         + (size_t)row * N_P + lane * 4);
    const float4 dv = *(const float4*)&dL[lane * 4];
    float a = bf2f((unsigned short)sv[0]) * dv.x
            + bf2f((unsigned short)sv[1]) * dv.y
            + bf2f((unsigned short)sv[2]) * dv.z
            + bf2f((unsigned short)sv[3]) * dv.w;
    #pragma unroll
    for (int s = 32; s; s >>= 1) a += __shfl_xor(a, s);
    if (lane == 0) {
        const float d = dL[row];
        const float r = 1.0f / (d * a + 1e-9f);
        const float c = r * d;
        cArr[g * N_P + row] = c;
        wArr[g * N_P + row] = c * d;
    }
}

// ---------------------------------------------------------------------------
// K3: M = (S*diag(w)) @ S^T per graph (w folded into A-frag after LDS read).
// Q = Dd M Dc (masked) stored fp32 to compact Qb [96][256][256].
// Fragment stores to Qb are 64B-aligned full lines (row pitch 1024B) ->
// coalesced, unlike the 3000B-pitch output tensor. The wide-format output
// write is done by k_wr with a pure streaming pattern.
// ---------------------------------------------------------------------------
__global__ __launch_bounds__(256) void k_pp(
    const unsigned short* __restrict__ Sb, const float* __restrict__ rowsum,
    const float* __restrict__ cArr, const float* __restrict__ wArr,
    float* __restrict__ Qb)
{
    const int blk = (blockIdx.x & 7) * 192 + (blockIdx.x >> 3);  // XCD swizzle, 1536 blocks
    const int g   = blk >> 4;
    const int i0  = ((blk >> 2) & 3) << 6;
    const int j0  = (blk & 3) << 6;
    const int t    = threadIdx.x;
    const int w    = t >> 6;
    const int lane = t & 63;
    const int m = lane & 15, kg = lane >> 4;

    __shared__ __attribute__((aligned(16))) unsigned short As[64][40]; // 80B stride
    __shared__ __attribute__((aligned(16))) unsigned short Bs[64][40];
    __shared__ float dRow[64], cCol[64];
    __shared__ __attribute__((aligned(16))) float wL[N_P];

    if (t < 64) dRow[t] = rsqrtf(rowsum[g * N_P + i0 + t] + 1e-9f);
    else if (t < 128) cCol[t - 64] = cArr[g * N_P + j0 + (t - 64)];
    wL[t] = wArr[g * N_P + t];

    const unsigned short* Sg = Sb + (size_t)g * N_P * N_P;

    floatx4 acc[4];
    const floatx4 zero = {0.f, 0.f, 0.f, 0.f};
    #pragma unroll
    for (int tt = 0; tt < 4; ++tt) acc[tt] = zero;

    const int sr = t >> 2, sc = t & 3;   // staging: 16B per thread per matrix
    for (int kb = 0; kb < 8; ++kb) {
        __syncthreads();
        *(uint4*)&As[sr][sc * 8] = *(const uint4*)(Sg + (size_t)(i0 + sr) * N_P + kb * 32 + sc * 8);
        *(uint4*)&Bs[sr][sc * 8] = *(const uint4*)(Sg + (size_t)(j0 + sr) * N_P + kb * 32 + sc * 8);
        __syncthreads();
        const shortx8 a = *(const shortx8*)&As[(w << 4) + m][kg << 3];
        const float4 w0 = *(const float4*)&wL[kb * 32 + (kg << 3)];
        const float4 w1 = *(const float4*)&wL[kb * 32 + (kg << 3) + 4];
        const float wv[8] = {w0.x, w0.y, w0.z, w0.w, w1.x, w1.y, w1.z, w1.w};
        shortx8 aw;
        #pragma unroll
        for (int u = 0; u < 8; ++u)
            aw[u] = (short)f2bf(bf2f((unsigned short)a[u]) * wv[u]);
        #pragma unroll
        for (int tt = 0; tt < 4; ++tt) {
            const shortx8 b = *(const shortx8*)&Bs[(tt << 4) + m][kg << 3];
            acc[tt] = __builtin_amdgcn_mfma_f32_16x16x32_bf16(aw, b, acc[tt], 0, 0, 0);
        }
    }

    float dR[4], cC[4];
    #pragma unroll
    for (int r = 0; r < 4; ++r) dR[r] = dRow[(w << 4) + (kg << 2) + r];
    #pragma unroll
    for (int tt = 0; tt < 4; ++tt) cC[tt] = cCol[(tt << 4) + m];

    float* Qg = Qb + (size_t)g * N_P * N_P;
    #pragma unroll
    for (int tt = 0; tt < 4; ++tt) {
        #pragma unroll
        for (int r = 0; r < 4; ++r) {
            const int I = i0 + (w << 4) + (kg << 2) + r;
            const int J = j0 + (tt << 4) + m;
            const float q = (I == J) ? 0.f : acc[tt][r] * dR[r] * cC[tt];
            Qg[(size_t)I * N_P + J] = q;   // padded I/J>=250 stored but never read
        }
    }
}

// ---------------------------------------------------------------------------
// K4: pure streaming writer. Per row i: read S row (512B) + Q row (1KB)
// (L2-warm via matching g->XCD swizzle), compute p = dI*s*c_t on the fly,
// write 12 contiguous 1000B dword runs per row. Each block writes a
// contiguous ~24KB run per tensor -> full cache lines; nontemporal keeps
// the 288MB stream from evicting Sb/Qb.
// ---------------------------------------------------------------------------
__global__ __launch_bounds__(256) void k_wr(
    const unsigned short* __restrict__ Sb, const float* __restrict__ Qb,
    const float* __restrict__ rowsum, const float* __restrict__ cArr,
    float* __restrict__ out)
{
    const int blk = (blockIdx.x & 7) * 384 + (blockIdx.x >> 3);  // XCD swizzle, 3072 blocks
    const int g  = blk >> 5;
    const int i0 = (blk & 31) << 3;      // 8 rows per block
    const int t  = threadIdx.x;

    const float cT = (t < N_N) ? cArr[g * N_P + t] : 0.f;
    const unsigned short* Sg = Sb + (size_t)g * N_P * N_P;
    const float* Qg = Qb + (size_t)g * N_P * N_P;
    float* o0 = out + (size_t)g * OUT_GSTRIDE;
    float* o1 = o0 + (size_t)OUT_STRIDE;
    float* o2 = o0 + 2 * (size_t)OUT_STRIDE;
    float* o3 = o0 + 3 * (size_t)OUT_STRIDE;

    #pragma unroll 2
    for (int il = 0; il < 8; ++il) {
        const int i = i0 + il;
        if (i >= N_N) break;             // block-uniform
        const float dI = rsqrtf(rowsum[g * N_P + i] + 1e-9f);
        if (t < N_N) {
            const float s = bf2f(Sg[(size_t)i * N_P + t]);
            const float p = (t == i) ? 0.f : dI * s * cT;
            const float q = Qg[(size_t)i * N_P + t];
            const size_t base = (size_t)i * 750 + t;
            __builtin_nontemporal_store(p, o0 + base);
            __builtin_nontemporal_store(p, o0 + base + 250);
            __builtin_nontemporal_store(p, o0 + base + 500);
            __builtin_nontemporal_store(q, o1 + base);
            __builtin_nontemporal_store(q, o1 + base + 250);
            __builtin_nontemporal_store(q, o1 + base + 500);
            __builtin_nontemporal_store(p, o2 + base);
            __builtin_nontemporal_store(p, o2 + base + 250);
            __builtin_nontemporal_store(p, o2 + base + 500);
            __builtin_nontemporal_store(q, o3 + base);
            __builtin_nontemporal_store(q, o3 + base + 250);
            __builtin_nontemporal_store(q, o3 + base + 500);
        }
    }
}

extern "C" void kernel_launch(void* const* d_in, const int* in_sizes, int n_in,
                              void* d_out, int out_size, void* d_ws, size_t ws_size,
                              hipStream_t stream) {
    const float* hist  = (const float*)d_in[0];
    const float* prior = (const float*)d_in[1];
    const float* obs   = (const float*)d_in[2];
    const float* Wemb  = (const float*)d_in[3];
    const float* bemb  = (const float*)d_in[4];
    float* out = (float*)d_out;

    char* p = (char*)d_ws;
    unsigned short* nvb = (unsigned short*)p; p += (size_t)G_N * N_P * E_N * 2;   // 3.1 MB
    unsigned short* Sb  = (unsigned short*)p; p += (size_t)G_N * N_P * N_P * 2;   // 12.6 MB
    float* rowsum = (float*)p; p += (size_t)G_N * N_P * 4;
    float* cArr   = (float*)p; p += (size_t)G_N * N_P * 4;
    float* wArr   = (float*)p; p += (size_t)G_N * N_P * 4;
    float* Qb     = (float*)p; p += (size_t)G_N * N_P * N_P * 4;                  // 25.2 MB
    // total ~41.5 MB of ws

    k_embed<<<dim3(G_N * N_P / 64), dim3(256), 0, stream>>>(hist, prior, obs, Wemb, bemb, nvb);
    k_sim  <<<dim3(G_N * 16),       dim3(256), 0, stream>>>(nvb, Sb, rowsum);
    k_trans<<<dim3(G_N * 64),       dim3(256), 0, stream>>>(Sb, rowsum, cArr, wArr);
    k_pp   <<<dim3(G_N * 16),       dim3(256), 0, stream>>>(Sb, rowsum, cArr, wArr, Qb);
    k_wr   <<<dim3(G_N * 32),       dim3(256), 0, stream>>>(Sb, Qb, rowsum, cArr, out);
}

// Round 5
// 373.499 us; speedup vs baseline: 1.6013x; 1.1654x over previous
//
#include <hip/hip_runtime.h>
#include <hip/hip_bf16.h>

#define G_N 96
#define N_N 250
#define N_P 256
#define E_N 64
#define OUT_GSTRIDE (250 * 750)          // per-graph slab inside one output tensor (floats)
#define OUT_STRIDE  (96 * 250 * 750)     // 18,000,000 floats per output tensor

typedef __attribute__((ext_vector_type(4))) float floatx4;
typedef __attribute__((ext_vector_type(8))) short shortx8;
typedef __attribute__((ext_vector_type(4))) short shortx4;

__device__ __forceinline__ float bf2f(unsigned short u) {
    union { unsigned int i; float f; } v; v.i = ((unsigned int)u) << 16; return v.f;
}
__device__ __forceinline__ unsigned short f2bf(float f) {
    union { float f; unsigned int i; } v; v.f = f;
    unsigned int x = v.i;
    return (unsigned short)((x + 0x7fffu + ((x >> 16) & 1u)) >> 16);  // RNE
}

// ---------------------------------------------------------------------------
// K1: nodevec = tanh(concat(hist,prior,obs) @ W + b)  -> bf16 [96][256][64]
// ---------------------------------------------------------------------------
__global__ __launch_bounds__(256) void k_embed(
    const float* __restrict__ hist, const float* __restrict__ prior,
    const float* __restrict__ obs, const float* __restrict__ Wemb,
    const float* __restrict__ bemb, unsigned short* __restrict__ nvb)
{
    __shared__ __attribute__((aligned(16))) float Xt[32][68];  // [k][n], pad 68
    __shared__ __attribute__((aligned(16))) float Wl[32][64];  // [k][e]
    const int t  = threadIdx.x;
    const int tx = t & 15, ty = t >> 4;
    const int rr0 = blockIdx.x * 64;   // padded row base; 64 | 256 so g uniform
    const int g   = rr0 >> 8;
    const int n0  = rr0 & 255;

    float acc[4][4] = {};

    for (int c = 0; c < 7; ++c) {      // 7 K-chunks of 32; source boundaries align
        const float* src; int rowlen, off;
        if (c < 4)      { src = hist;  rowlen = 128; off = c << 5; }
        else if (c < 6) { src = prior; rowlen = 64;  off = (c - 4) << 5; }
        else            { src = obs;   rowlen = 32;  off = 0; }
        __syncthreads();
        {   // stage X chunk transposed: 64 rows x 32 d
            const int d  = t & 31;
            const int nb = t >> 5;
            #pragma unroll
            for (int p = 0; p < 8; ++p) {
                const int nl = nb + p * 8;
                const int n  = n0 + nl;
                float v = 0.0f;
                if (n < N_N) v = src[(size_t)(g * N_N + n) * rowlen + off + d];
                Xt[d][nl] = v;
            }
        }
        {   // stage W chunk: 32 d x 64 e
            const int e  = t & 63;
            const int db = t >> 6;
            #pragma unroll
            for (int p = 0; p < 8; ++p) {
                const int dl = db + p * 4;
                Wl[dl][e] = Wemb[(c * 32 + dl) * 64 + e];
            }
        }
        __syncthreads();
        #pragma unroll
        for (int k = 0; k < 32; ++k) {
            const float4 av = *(const float4*)&Xt[k][4 * ty];
            const float4 bv = *(const float4*)&Wl[k][4 * tx];
            const float a[4] = {av.x, av.y, av.z, av.w};
            const float b[4] = {bv.x, bv.y, bv.z, bv.w};
            #pragma unroll
            for (int r = 0; r < 4; ++r)
                #pragma unroll
                for (int cc = 0; cc < 4; ++cc)
                    acc[r][cc] = fmaf(a[r], b[cc], acc[r][cc]);
        }
    }
    #pragma unroll
    for (int r = 0; r < 4; ++r) {
        const int nl = 4 * ty + r;
        const int n  = n0 + nl;
        unsigned short* d2 = nvb + ((size_t)g * N_P + (n0 + nl)) * E_N + 4 * tx;
        #pragma unroll
        for (int cc = 0; cc < 4; ++cc) {
            float v = 0.0f;
            if (n < N_N) v = tanhf(acc[r][cc] + bemb[4 * tx + cc]);
            d2[cc] = f2bf(v);
        }
    }
}

// ---------------------------------------------------------------------------
// K2a: S = relu(nv @ nv^T) per graph (bf16 MFMA 16x16x32, K=64) + fp32
// rowsums. Block owns 16 full rows (256 cols) -> rowsum needs no atomics.
// ---------------------------------------------------------------------------
__global__ __launch_bounds__(256) void k_sim(
    const unsigned short* __restrict__ nvb, unsigned short* __restrict__ Sb,
    float* __restrict__ rowsum)
{
    const int blk = blockIdx.x;          // 96*16
    const int g   = blk >> 4;
    const int i0  = (blk & 15) << 4;
    const int t    = threadIdx.x;
    const int w    = t >> 6;
    const int lane = t & 63;
    const int m = lane & 15, kg = lane >> 4;

    const shortx8* nvg = (const shortx8*)(nvb + (size_t)g * N_P * E_N);
    const shortx8 a0 = nvg[(i0 + m) * 8 + kg];       // k in [8kg, 8kg+8)
    const shortx8 a1 = nvg[(i0 + m) * 8 + 4 + kg];   // k in [32+8kg, ...)

    floatx4 acc[4];
    const floatx4 zero = {0.f, 0.f, 0.f, 0.f};
    #pragma unroll
    for (int tt = 0; tt < 4; ++tt) {
        const int j = (w << 6) + (tt << 4) + m;      // B-frag: n=lane&15, row-major nv
        const shortx8 b0 = nvg[j * 8 + kg];
        const shortx8 b1 = nvg[j * 8 + 4 + kg];
        floatx4 c = zero;
        c = __builtin_amdgcn_mfma_f32_16x16x32_bf16(a0, b0, c, 0, 0, 0);
        c = __builtin_amdgcn_mfma_f32_16x16x32_bf16(a1, b1, c, 0, 0, 0);
        acc[tt] = c;
    }

    float v[4] = {0.f, 0.f, 0.f, 0.f};
    unsigned short* Sg = Sb + (size_t)g * N_P * N_P;
    #pragma unroll
    for (int tt = 0; tt < 4; ++tt) {
        #pragma unroll
        for (int r = 0; r < 4; ++r) {
            float s = acc[tt][r];
            s = s > 0.f ? s : 0.f;                   // relu
            const int il = (kg << 2) + r;            // C/D: row=(lane>>4)*4+reg
            const int j  = (w << 6) + (tt << 4) + m; // col=lane&15
            Sg[(size_t)(i0 + il) * N_P + j] = f2bf(s);
            v[r] += s;
        }
    }
    #pragma unroll
    for (int r = 0; r < 4; ++r) {                    // reduce over m (16 lanes)
        v[r] += __shfl_xor(v[r], 1);
        v[r] += __shfl_xor(v[r], 2);
        v[r] += __shfl_xor(v[r], 4);
        v[r] += __shfl_xor(v[r], 8);
    }
    __shared__ float rs[4][16];
    if (m == 0) {
        #pragma unroll
        for (int r = 0; r < 4; ++r) rs[w][(kg << 2) + r] = v[r];
    }
    __syncthreads();
    if (t < 16) rowsum[g * N_P + i0 + t] = rs[0][t] + rs[1][t] + rs[2][t] + rs[3][t];
}

// ---------------------------------------------------------------------------
// K2b: t_i = sum_j S_ij d_j ; r=1/(d_i t_i+1e-9); c=r*d; w=c*d
// Wave-per-row, fully coalesced. 96*64 blocks.
// ---------------------------------------------------------------------------
__global__ __launch_bounds__(256) void k_trans(
    const unsigned short* __restrict__ Sb, const float* __restrict__ rowsum,
    float* __restrict__ cArr, float* __restrict__ wArr)
{
    const int blk = (blockIdx.x & 7) * 768 + (blockIdx.x >> 3);  // XCD swizzle, 6144 blocks
    const int g  = blk >> 6;
    const int r0 = (blk & 63) << 2;      // 4 rows per block, one per wave
    const int t = threadIdx.x;
    const int w = t >> 6, lane = t & 63;
    __shared__ __attribute__((aligned(16))) float dL[N_P];
    dL[t] = rsqrtf(rowsum[g * N_P + t] + 1e-9f);
    __syncthreads();
    const int row = r0 + w;
    const shortx4 sv = *(const shortx4*)(Sb + (size_t)g * N_P * N_P
                                         + (size_t)row * N_P + lane * 4);
    const float4 dv = *(const float4*)&dL[lane * 4];
    float a = bf2f((unsigned short)sv[0]) * dv.x
            + bf2f((unsigned short)sv[1]) * dv.y
            + bf2f((unsigned short)sv[2]) * dv.z
            + bf2f((unsigned short)sv[3]) * dv.w;
    #pragma unroll
    for (int s = 32; s; s >>= 1) a += __shfl_xor(a, s);
    if (lane == 0) {
        const float d = dL[row];
        const float r = 1.0f / (d * a + 1e-9f);
        const float c = r * d;
        cArr[g * N_P + row] = c;
        wArr[g * N_P + row] = c * d;
    }
}

// ---------------------------------------------------------------------------
// K3 (fused compute + writer): block = (g, 16-row stripe).
//  - MFMA: M-stripe = (S_stripe * diag(w)) @ S^T  (B = all 256 rows of S,
//    staged per 32-k chunk), q = Dd M Dc masked -> qAll LDS [16][257] fp32.
//  - p = Dd S Dc masked built from the A-chunk staging  -> pAll LDS.
//  - Streaming: rows written in EVEN PAIRS: a pair's 6000B span per tensor
//    is exactly 375 16B-aligned float4 stores (1KB/wave-instr). The x3
//    tiling is an LDS gather (f%750%250). Writes all 288MB of output.
//  - Plain (non-NT) stores: during the stream phase nothing precious is in
//    L2 anymore (S/nv already consumed), and fillBuffer proves plain wide
//    stores reach 6.2 TB/s.
// ---------------------------------------------------------------------------
__global__ __launch_bounds__(256) void k_pq(
    const unsigned short* __restrict__ Sb, const float* __restrict__ rowsum,
    const float* __restrict__ cArr, const float* __restrict__ wArr,
    float* __restrict__ out)
{
    const int blk = (blockIdx.x & 7) * 192 + (blockIdx.x >> 3);  // XCD swizzle, 1536 blocks
    const int g   = blk >> 4;
    const int i0  = (blk & 15) << 4;     // 16-row stripe
    const int t    = threadIdx.x;
    const int w    = t >> 6;
    const int lane = t & 63;
    const int m = lane & 15, kg = lane >> 4;

    __shared__ __attribute__((aligned(16))) unsigned short As[16][40];   // stripe rows x 32k
    __shared__ __attribute__((aligned(16))) unsigned short Bs[256][40];  // all rows x 32k
    __shared__ __attribute__((aligned(16))) float wL[N_P];
    __shared__ __attribute__((aligned(16))) float cC[N_P];
    __shared__ float dR16[16];
    __shared__ __attribute__((aligned(16))) float pAll[16][257];
    __shared__ __attribute__((aligned(16))) float qAll[16][257];

    wL[t] = wArr[g * N_P + t];
    cC[t] = cArr[g * N_P + t];
    if (t < 16) dR16[t] = rsqrtf(rowsum[g * N_P + i0 + t] + 1e-9f);

    const unsigned short* Sg = Sb + (size_t)g * N_P * N_P;

    floatx4 acc[4];
    const floatx4 zero = {0.f, 0.f, 0.f, 0.f};
    #pragma unroll
    for (int tt = 0; tt < 4; ++tt) acc[tt] = zero;

    for (int kb = 0; kb < 8; ++kb) {
        __syncthreads();
        if (t < 64) {      // stage A chunk: 16 rows x 32 k (64 x uint4)
            const int row = t >> 2, c4 = t & 3;
            *(uint4*)&As[row][c4 * 8] =
                *(const uint4*)(Sg + (size_t)(i0 + row) * N_P + kb * 32 + c4 * 8);
        }
        #pragma unroll
        for (int q4 = 0; q4 < 4; ++q4) {   // stage B chunk: 256 rows x 32 k (1024 x uint4)
            const int u = t + (q4 << 8);
            const int row = u >> 2, c4 = u & 3;
            *(uint4*)&Bs[row][c4 * 8] =
                *(const uint4*)(Sg + (size_t)row * N_P + kb * 32 + c4 * 8);
        }
        __syncthreads();
        // build p slice for this k-chunk (cols kb*32..kb*32+31)
        #pragma unroll
        for (int q2 = 0; q2 < 2; ++q2) {
            const int idx = t + (q2 << 8);
            const int row = idx >> 5, kl = idx & 31;
            const int col = kb * 32 + kl;
            float pv = dR16[row] * bf2f(As[row][kl]) * cC[col];
            if (i0 + row == col) pv = 0.f;
            pAll[row][col] = pv;
        }
        // MFMA: A-frag (w folded), B-frags per wave column block
        const shortx8 a = *(const shortx8*)&As[m][kg << 3];
        const float4 w0 = *(const float4*)&wL[kb * 32 + (kg << 3)];
        const float4 w1 = *(const float4*)&wL[kb * 32 + (kg << 3) + 4];
        const float wv[8] = {w0.x, w0.y, w0.z, w0.w, w1.x, w1.y, w1.z, w1.w};
        shortx8 aw;
        #pragma unroll
        for (int u = 0; u < 8; ++u)
            aw[u] = (short)f2bf(bf2f((unsigned short)a[u]) * wv[u]);
        #pragma unroll
        for (int tt = 0; tt < 4; ++tt) {
            const shortx8 b = *(const shortx8*)&Bs[(w << 6) + (tt << 4) + m][kg << 3];
            acc[tt] = __builtin_amdgcn_mfma_f32_16x16x32_bf16(aw, b, acc[tt], 0, 0, 0);
        }
    }

    // q -> LDS (C/D layout: row = kg*4+r in stripe, col = w*64 + tt*16 + m)
    #pragma unroll
    for (int tt = 0; tt < 4; ++tt) {
        #pragma unroll
        for (int r = 0; r < 4; ++r) {
            const int lrow = (kg << 2) + r;
            const int col  = (w << 6) + (tt << 4) + m;
            float qv = acc[tt][r] * dR16[lrow] * cC[col];
            if (i0 + lrow == col) qv = 0.f;
            qAll[lrow][col] = qv;
        }
    }
    __syncthreads();

    // stream: 8 row-pairs x 4 tensors x 375 float4 (all 16B-aligned)
    for (int pr = 0; pr < 8; ++pr) {
        const int i = i0 + (pr << 1);
        if (i >= N_N) break;             // 250 even: pairs never straddle validity
        const float* pRow = &pAll[pr << 1][0];
        const float* qRow = &qAll[pr << 1][0];
        const size_t slab = (size_t)g * OUT_GSTRIDE + (size_t)i * 750;
        for (int u = t; u < 1500; u += 256) {
            const int tsel = (u >= 750) ? ((u >= 1125) ? 3 : 2) : ((u >= 375) ? 1 : 0);
            const int within = u - tsel * 375;
            const int f0 = within << 2;
            const float* src = (tsel & 1) ? qRow : pRow;
            float v[4];
            #pragma unroll
            for (int c = 0; c < 4; ++c) {
                const int f  = f0 + c;
                const int r2 = (f >= 750) ? 1 : 0;
                int cc = f - r2 * 750;
                if (cc >= 500) cc -= 500; else if (cc >= 250) cc -= 250;
                v[c] = src[r2 * 257 + cc];
            }
            floatx4 vv = {v[0], v[1], v[2], v[3]};
            *(floatx4*)(out + (size_t)tsel * OUT_STRIDE + slab + f0) = vv;
        }
    }
}

extern "C" void kernel_launch(void* const* d_in, const int* in_sizes, int n_in,
                              void* d_out, int out_size, void* d_ws, size_t ws_size,
                              hipStream_t stream) {
    const float* hist  = (const float*)d_in[0];
    const float* prior = (const float*)d_in[1];
    const float* obs   = (const float*)d_in[2];
    const float* Wemb  = (const float*)d_in[3];
    const float* bemb  = (const float*)d_in[4];
    float* out = (float*)d_out;

    char* p = (char*)d_ws;
    unsigned short* nvb = (unsigned short*)p; p += (size_t)G_N * N_P * E_N * 2;   // 3.1 MB
    unsigned short* Sb  = (unsigned short*)p; p += (size_t)G_N * N_P * N_P * 2;   // 12.6 MB
    float* rowsum = (float*)p; p += (size_t)G_N * N_P * 4;
    float* cArr   = (float*)p; p += (size_t)G_N * N_P * 4;
    float* wArr   = (float*)p; p += (size_t)G_N * N_P * 4;
    // total ~16 MB of ws

    k_embed<<<dim3(G_N * N_P / 64), dim3(256), 0, stream>>>(hist, prior, obs, Wemb, bemb, nvb);
    k_sim  <<<dim3(G_N * 16),       dim3(256), 0, stream>>>(nvb, Sb, rowsum);
    k_trans<<<dim3(G_N * 64),       dim3(256), 0, stream>>>(Sb, rowsum, cArr, wArr);
    k_pq   <<<dim3(G_N * 16),       dim3(256), 0, stream>>>(Sb, rowsum, cArr, wArr, out);
}

// Round 6
// 369.915 us; speedup vs baseline: 1.6168x; 1.0097x over previous
//
#include <hip/hip_runtime.h>
#include <hip/hip_bf16.h>

#define G_N 96
#define N_N 250
#define N_P 256
#define E_N 64
#define OUT_GSTRIDE (250 * 750)          // per-graph slab inside one output tensor (floats)
#define OUT_STRIDE  (96 * 250 * 750)     // 18,000,000 floats per output tensor

typedef __attribute__((ext_vector_type(4))) float floatx4;
typedef __attribute__((ext_vector_type(2))) float floatx2;
typedef __attribute__((ext_vector_type(8))) short shortx8;
typedef __attribute__((ext_vector_type(4))) short shortx4;

__device__ __forceinline__ float bf2f(unsigned short u) {
    union { unsigned int i; float f; } v; v.i = ((unsigned int)u) << 16; return v.f;
}
__device__ __forceinline__ unsigned short f2bf(float f) {
    union { float f; unsigned int i; } v; v.f = f;
    unsigned int x = v.i;
    return (unsigned short)((x + 0x7fffu + ((x >> 16) & 1u)) >> 16);  // RNE
}

// ---------------------------------------------------------------------------
// K1: nodevec = tanh(concat(hist,prior,obs) @ W + b)  -> bf16 [96][256][64]
// ---------------------------------------------------------------------------
__global__ __launch_bounds__(256) void k_embed(
    const float* __restrict__ hist, const float* __restrict__ prior,
    const float* __restrict__ obs, const float* __restrict__ Wemb,
    const float* __restrict__ bemb, unsigned short* __restrict__ nvb)
{
    __shared__ __attribute__((aligned(16))) float Xt[32][68];  // [k][n], pad 68
    __shared__ __attribute__((aligned(16))) float Wl[32][64];  // [k][e]
    const int t  = threadIdx.x;
    const int tx = t & 15, ty = t >> 4;
    const int rr0 = blockIdx.x * 64;   // padded row base; 64 | 256 so g uniform
    const int g   = rr0 >> 8;
    const int n0  = rr0 & 255;

    float acc[4][4] = {};

    for (int c = 0; c < 7; ++c) {      // 7 K-chunks of 32; source boundaries align
        const float* src; int rowlen, off;
        if (c < 4)      { src = hist;  rowlen = 128; off = c << 5; }
        else if (c < 6) { src = prior; rowlen = 64;  off = (c - 4) << 5; }
        else            { src = obs;   rowlen = 32;  off = 0; }
        __syncthreads();
        {   // stage X chunk transposed: 64 rows x 32 d
            const int d  = t & 31;
            const int nb = t >> 5;
            #pragma unroll
            for (int p = 0; p < 8; ++p) {
                const int nl = nb + p * 8;
                const int n  = n0 + nl;
                float v = 0.0f;
                if (n < N_N) v = src[(size_t)(g * N_N + n) * rowlen + off + d];
                Xt[d][nl] = v;
            }
        }
        {   // stage W chunk: 32 d x 64 e
            const int e  = t & 63;
            const int db = t >> 6;
            #pragma unroll
            for (int p = 0; p < 8; ++p) {
                const int dl = db + p * 4;
                Wl[dl][e] = Wemb[(c * 32 + dl) * 64 + e];
            }
        }
        __syncthreads();
        #pragma unroll
        for (int k = 0; k < 32; ++k) {
            const float4 av = *(const float4*)&Xt[k][4 * ty];
            const float4 bv = *(const float4*)&Wl[k][4 * tx];
            const float a[4] = {av.x, av.y, av.z, av.w};
            const float b[4] = {bv.x, bv.y, bv.z, bv.w};
            #pragma unroll
            for (int r = 0; r < 4; ++r)
                #pragma unroll
                for (int cc = 0; cc < 4; ++cc)
                    acc[r][cc] = fmaf(a[r], b[cc], acc[r][cc]);
        }
    }
    #pragma unroll
    for (int r = 0; r < 4; ++r) {
        const int nl = 4 * ty + r;
        const int n  = n0 + nl;
        unsigned short* d2 = nvb + ((size_t)g * N_P + (n0 + nl)) * E_N + 4 * tx;
        #pragma unroll
        for (int cc = 0; cc < 4; ++cc) {
            float v = 0.0f;
            if (n < N_N) v = tanhf(acc[r][cc] + bemb[4 * tx + cc]);
            d2[cc] = f2bf(v);
        }
    }
}

// ---------------------------------------------------------------------------
// K2a: S = relu(nv @ nv^T) per graph (bf16 MFMA 16x16x32, K=64) + fp32
// rowsums. Block owns 16 full rows (256 cols) -> rowsum needs no atomics.
// ---------------------------------------------------------------------------
__global__ __launch_bounds__(256) void k_sim(
    const unsigned short* __restrict__ nvb, unsigned short* __restrict__ Sb,
    float* __restrict__ rowsum)
{
    const int blk = blockIdx.x;          // 96*16
    const int g   = blk >> 4;
    const int i0  = (blk & 15) << 4;
    const int t    = threadIdx.x;
    const int w    = t >> 6;
    const int lane = t & 63;
    const int m = lane & 15, kg = lane >> 4;

    const shortx8* nvg = (const shortx8*)(nvb + (size_t)g * N_P * E_N);
    const shortx8 a0 = nvg[(i0 + m) * 8 + kg];       // k in [8kg, 8kg+8)
    const shortx8 a1 = nvg[(i0 + m) * 8 + 4 + kg];   // k in [32+8kg, ...)

    floatx4 acc[4];
    const floatx4 zero = {0.f, 0.f, 0.f, 0.f};
    #pragma unroll
    for (int tt = 0; tt < 4; ++tt) {
        const int j = (w << 6) + (tt << 4) + m;      // B-frag: n=lane&15, row-major nv
        const shortx8 b0 = nvg[j * 8 + kg];
        const shortx8 b1 = nvg[j * 8 + 4 + kg];
        floatx4 c = zero;
        c = __builtin_amdgcn_mfma_f32_16x16x32_bf16(a0, b0, c, 0, 0, 0);
        c = __builtin_amdgcn_mfma_f32_16x16x32_bf16(a1, b1, c, 0, 0, 0);
        acc[tt] = c;
    }

    float v[4] = {0.f, 0.f, 0.f, 0.f};
    unsigned short* Sg = Sb + (size_t)g * N_P * N_P;
    #pragma unroll
    for (int tt = 0; tt < 4; ++tt) {
        #pragma unroll
        for (int r = 0; r < 4; ++r) {
            float s = acc[tt][r];
            s = s > 0.f ? s : 0.f;                   // relu
            const int il = (kg << 2) + r;            // C/D: row=(lane>>4)*4+reg
            const int j  = (w << 6) + (tt << 4) + m; // col=lane&15
            Sg[(size_t)(i0 + il) * N_P + j] = f2bf(s);
            v[r] += s;
        }
    }
    #pragma unroll
    for (int r = 0; r < 4; ++r) {                    // reduce over m (16 lanes)
        v[r] += __shfl_xor(v[r], 1);
        v[r] += __shfl_xor(v[r], 2);
        v[r] += __shfl_xor(v[r], 4);
        v[r] += __shfl_xor(v[r], 8);
    }
    __shared__ float rs[4][16];
    if (m == 0) {
        #pragma unroll
        for (int r = 0; r < 4; ++r) rs[w][(kg << 2) + r] = v[r];
    }
    __syncthreads();
    if (t < 16) rowsum[g * N_P + i0 + t] = rs[0][t] + rs[1][t] + rs[2][t] + rs[3][t];
}

// ---------------------------------------------------------------------------
// K2b: t_i = sum_j S_ij d_j ; r=1/(d_i t_i+1e-9); c=r*d; w=c*d
// Wave-per-row, fully coalesced. 96*64 blocks.
// ---------------------------------------------------------------------------
__global__ __launch_bounds__(256) void k_trans(
    const unsigned short* __restrict__ Sb, const float* __restrict__ rowsum,
    float* __restrict__ cArr, float* __restrict__ wArr)
{
    const int blk = (blockIdx.x & 7) * 768 + (blockIdx.x >> 3);  // XCD swizzle, 6144 blocks
    const int g  = blk >> 6;
    const int r0 = (blk & 63) << 2;      // 4 rows per block, one per wave
    const int t = threadIdx.x;
    const int w = t >> 6, lane = t & 63;
    __shared__ __attribute__((aligned(16))) float dL[N_P];
    dL[t] = rsqrtf(rowsum[g * N_P + t] + 1e-9f);
    __syncthreads();
    const int row = r0 + w;
    const shortx4 sv = *(const shortx4*)(Sb + (size_t)g * N_P * N_P
                                         + (size_t)row * N_P + lane * 4);
    const float4 dv = *(const float4*)&dL[lane * 4];
    float a = bf2f((unsigned short)sv[0]) * dv.x
            + bf2f((unsigned short)sv[1]) * dv.y
            + bf2f((unsigned short)sv[2]) * dv.z
            + bf2f((unsigned short)sv[3]) * dv.w;
    #pragma unroll
    for (int s = 32; s; s >>= 1) a += __shfl_xor(a, s);
    if (lane == 0) {
        const float d = dL[row];
        const float r = 1.0f / (d * a + 1e-9f);
        const float c = r * d;
        cArr[g * N_P + row] = c;
        wArr[g * N_P + row] = c * d;
    }
}

// ---------------------------------------------------------------------------
// K3 (fused compute + writer): block = (g, 16-row stripe).
//  - MFMA: M-stripe = (S_stripe * diag(w)) @ S^T, q = Dd M Dc -> qAll LDS.
//  - p = Dd S Dc built during A-chunk staging -> pAll LDS.
//  - Write phase v2: lane L does ONE contiguous ds_read_b128 of row floats
//    [4L..4L+3] (canonical conflict-free pattern, m134) and replicates from
//    registers: x3 tiling = 3 stores at +0/+250/+500 (compile-time offsets),
//    x4 tensors. All stores float2 (8B) -- every replica offset is 8B-
//    aligned for every row parity (row pitch 3000B). No mod arithmetic.
// ---------------------------------------------------------------------------
__global__ __launch_bounds__(256) void k_pq(
    const unsigned short* __restrict__ Sb, const float* __restrict__ rowsum,
    const float* __restrict__ cArr, const float* __restrict__ wArr,
    float* __restrict__ out)
{
    const int blk = (blockIdx.x & 7) * 192 + (blockIdx.x >> 3);  // XCD swizzle, 1536 blocks
    const int g   = blk >> 4;
    const int i0  = (blk & 15) << 4;     // 16-row stripe
    const int t    = threadIdx.x;
    const int w    = t >> 6;
    const int lane = t & 63;
    const int m = lane & 15, kg = lane >> 4;

    __shared__ __attribute__((aligned(16))) unsigned short As[16][40];   // stripe rows x 32k
    __shared__ __attribute__((aligned(16))) unsigned short Bs[256][40];  // all rows x 32k
    __shared__ __attribute__((aligned(16))) float wL[N_P];
    __shared__ __attribute__((aligned(16))) float cC[N_P];
    __shared__ float dR16[16];
    __shared__ __attribute__((aligned(16))) float pAll[16][260];  // stride 260: 16B rows
    __shared__ __attribute__((aligned(16))) float qAll[16][260];

    wL[t] = wArr[g * N_P + t];
    cC[t] = cArr[g * N_P + t];
    if (t < 16) dR16[t] = rsqrtf(rowsum[g * N_P + i0 + t] + 1e-9f);

    const unsigned short* Sg = Sb + (size_t)g * N_P * N_P;

    floatx4 acc[4];
    const floatx4 zero = {0.f, 0.f, 0.f, 0.f};
    #pragma unroll
    for (int tt = 0; tt < 4; ++tt) acc[tt] = zero;

    for (int kb = 0; kb < 8; ++kb) {
        __syncthreads();
        if (t < 64) {      // stage A chunk: 16 rows x 32 k (64 x uint4)
            const int row = t >> 2, c4 = t & 3;
            *(uint4*)&As[row][c4 * 8] =
                *(const uint4*)(Sg + (size_t)(i0 + row) * N_P + kb * 32 + c4 * 8);
        }
        #pragma unroll
        for (int q4 = 0; q4 < 4; ++q4) {   // stage B chunk: 256 rows x 32 k (1024 x uint4)
            const int u = t + (q4 << 8);
            const int row = u >> 2, c4 = u & 3;
            *(uint4*)&Bs[row][c4 * 8] =
                *(const uint4*)(Sg + (size_t)row * N_P + kb * 32 + c4 * 8);
        }
        __syncthreads();
        // build p slice for this k-chunk (cols kb*32..kb*32+31)
        #pragma unroll
        for (int q2 = 0; q2 < 2; ++q2) {
            const int idx = t + (q2 << 8);
            const int row = idx >> 5, kl = idx & 31;
            const int col = kb * 32 + kl;
            float pv = dR16[row] * bf2f(As[row][kl]) * cC[col];
            if (i0 + row == col) pv = 0.f;
            pAll[row][col] = pv;
        }
        // MFMA: A-frag (w folded), B-frags per wave column block
        const shortx8 a = *(const shortx8*)&As[m][kg << 3];
        const float4 w0 = *(const float4*)&wL[kb * 32 + (kg << 3)];
        const float4 w1 = *(const float4*)&wL[kb * 32 + (kg << 3) + 4];
        const float wv[8] = {w0.x, w0.y, w0.z, w0.w, w1.x, w1.y, w1.z, w1.w};
        shortx8 aw;
        #pragma unroll
        for (int u = 0; u < 8; ++u)
            aw[u] = (short)f2bf(bf2f((unsigned short)a[u]) * wv[u]);
        #pragma unroll
        for (int tt = 0; tt < 4; ++tt) {
            const shortx8 b = *(const shortx8*)&Bs[(w << 6) + (tt << 4) + m][kg << 3];
            acc[tt] = __builtin_amdgcn_mfma_f32_16x16x32_bf16(aw, b, acc[tt], 0, 0, 0);
        }
    }

    // q -> LDS (C/D layout: row = kg*4+r in stripe, col = w*64 + tt*16 + m)
    #pragma unroll
    for (int tt = 0; tt < 4; ++tt) {
        #pragma unroll
        for (int r = 0; r < 4; ++r) {
            const int lrow = (kg << 2) + r;
            const int col  = (w << 6) + (tt << 4) + m;
            float qv = acc[tt][r] * dR16[lrow] * cC[col];
            if (i0 + lrow == col) qv = 0.f;
            qAll[lrow][col] = qv;
        }
    }
    __syncthreads();

    // ---- write phase v2: wave w owns rows {w, w+4, w+8, w+12}.
    // Lane L (<63) covers row floats [4L..4L+3]; lane 62 only xy valid
    // (row len 250 = 62*4+2); lane 63 idle. Per float2: 12 stores
    // (3 reps x 4 tensors), all 8B-aligned, replica offsets are
    // compile-time store immediates (1000B / 2000B).
    for (int rr = 0; rr < 4; ++rr) {
        const int row = (rr << 2) + w;
        const int i   = i0 + row;
        if (i >= N_N) continue;                    // wave-uniform
        const floatx4 p4 = *(const floatx4*)&pAll[row][lane << 2];
        const floatx4 q4 = *(const floatx4*)&qAll[row][lane << 2];
        if (lane >= 63) continue;
        const floatx2 pxy = {p4[0], p4[1]}, pzw = {p4[2], p4[3]};
        const floatx2 qxy = {q4[0], q4[1]}, qzw = {q4[2], q4[3]};
        float* b0 = out + (size_t)g * OUT_GSTRIDE + (size_t)i * 750 + (lane << 2);
        float* b1 = b0 + (size_t)OUT_STRIDE;
        float* b2 = b0 + 2 * (size_t)OUT_STRIDE;
        float* b3 = b0 + 3 * (size_t)OUT_STRIDE;
        #pragma unroll
        for (int rep = 0; rep < 3; ++rep) {
            const int o = rep * 250;
            *(floatx2*)(b0 + o) = pxy;
            *(floatx2*)(b1 + o) = qxy;
            *(floatx2*)(b2 + o) = pxy;
            *(floatx2*)(b3 + o) = qxy;
            if (lane < 62) {
                *(floatx2*)(b0 + o + 2) = pzw;
                *(floatx2*)(b1 + o + 2) = qzw;
                *(floatx2*)(b2 + o + 2) = pzw;
                *(floatx2*)(b3 + o + 2) = qzw;
            }
        }
    }
}

extern "C" void kernel_launch(void* const* d_in, const int* in_sizes, int n_in,
                              void* d_out, int out_size, void* d_ws, size_t ws_size,
                              hipStream_t stream) {
    const float* hist  = (const float*)d_in[0];
    const float* prior = (const float*)d_in[1];
    const float* obs   = (const float*)d_in[2];
    const float* Wemb  = (const float*)d_in[3];
    const float* bemb  = (const float*)d_in[4];
    float* out = (float*)d_out;

    char* p = (char*)d_ws;
    unsigned short* nvb = (unsigned short*)p; p += (size_t)G_N * N_P * E_N * 2;   // 3.1 MB
    unsigned short* Sb  = (unsigned short*)p; p += (size_t)G_N * N_P * N_P * 2;   // 12.6 MB
    float* rowsum = (float*)p; p += (size_t)G_N * N_P * 4;
    float* cArr   = (float*)p; p += (size_t)G_N * N_P * 4;
    float* wArr   = (float*)p; p += (size_t)G_N * N_P * 4;
    // total ~16 MB of ws

    k_embed<<<dim3(G_N * N_P / 64), dim3(256), 0, stream>>>(hist, prior, obs, Wemb, bemb, nvb);
    k_sim  <<<dim3(G_N * 16),       dim3(256), 0, stream>>>(nvb, Sb, rowsum);
    k_trans<<<dim3(G_N * 64),       dim3(256), 0, stream>>>(Sb, rowsum, cArr, wArr);
    k_pq   <<<dim3(G_N * 16),       dim3(256), 0, stream>>>(Sb, rowsum, cArr, wArr, out);
}